// Round 4
// baseline (36339.746 us; speedup 1.0000x reference)
//
#include <hip/hip_runtime.h>
#include <math.h>

#define BB 128
#define TT 1024
#define FF 64
#define HH 512
#define G4 2048            // 4*HH gate rows
#define NI 8
#define NJ 32
#define BT 16
#define NBLK 256
#define LDK 520            // padded K row (elems): 1040B stride -> 2-way banks only

typedef float f32x4 __attribute__((ext_vector_type(4)));
typedef short s16x8 __attribute__((ext_vector_type(8)));
typedef unsigned short u16;

// ---- canonical fp32 copies of all inputs (dtype-agnostic) ----
__device__ float g_ts[BB * TT * FF];
__device__ float g_wihe[G4 * FF];
__device__ float g_whhe[G4 * HH];
__device__ float g_bihe[G4], g_bhhe[G4], g_bihd[G4], g_bhhd[G4];
__device__ float g_wihd[G4 * FF];
__device__ float g_whhd[G4 * HH];
__device__ float g_wout[FF * HH];
__device__ float g_bout[FF];
// ---- inter-block state ----
__device__ u16   g_hbuf[2 * 2 * BB * HH];        // [parity][hi/lo][BB][HH]
__device__ float g_part[2 * NI * NJ * BT * FF];  // [parity][i][j][bt][ff]
__device__ int   g_isbf16;

__device__ __forceinline__ float bf2f(u16 u) {
  union { unsigned u; float f; } x; x.u = ((unsigned)u) << 16; return x.f;
}
__device__ __forceinline__ u16 f2bf(float f) {
  union { float f; unsigned u; } x; x.f = f;
  unsigned r = x.u + 0x7fffu + ((x.u >> 16) & 1u);
  return (u16)(r >> 16);
}

__device__ __forceinline__ void gbar(unsigned* bar, unsigned target) {
  __syncthreads();
  if (threadIdx.x == 0) {
    __hip_atomic_fetch_add(bar, 1u, __ATOMIC_RELEASE, __HIP_MEMORY_SCOPE_AGENT);
    while (__hip_atomic_load(bar, __ATOMIC_RELAXED, __HIP_MEMORY_SCOPE_AGENT) < target)
      __builtin_amdgcn_s_sleep(1);
    (void)__hip_atomic_load(bar, __ATOMIC_ACQUIRE, __HIP_MEMORY_SCOPE_AGENT);
  }
  __syncthreads();
}

// ---- dtype sniffer: bf16 exponent byte vs fp32 mantissa bits at dword bits[15:8] ----
__global__ void sniff_kernel(const void* wout) {
  __shared__ int cnt[64];
  int t = threadIdx.x;
  const unsigned* d = (const unsigned*)wout;
  int c = 0;
  for (int k = t; k < 1024; k += 64) {
    unsigned b = (d[k] >> 8) & 0x7fu;
    c += (b >= 0x30u && b <= 0x3eu) ? 1 : 0;
  }
  cnt[t] = c;
  __syncthreads();
  if (t == 0) {
    int s = 0;
    for (int k = 0; k < 64; ++k) s += cnt[k];
    g_isbf16 = (s > 512) ? 1 : 0;
  }
}

// destination resolved in DEVICE code — no host symbol lookups
__global__ void convert_kernel(const void* __restrict__ src, int which, int n) {
  int idx = blockIdx.x * 256 + threadIdx.x;
  if (idx >= n) return;
  float v;
  if (g_isbf16) v = bf2f(((const u16*)src)[idx]);
  else          v = ((const float*)src)[idx];
  float* dst;
  switch (which) {
    case 0: dst = g_ts;   break;
    case 1: dst = g_wihe; break;
    case 2: dst = g_whhe; break;
    case 3: dst = g_bihe; break;
    case 4: dst = g_bhhe; break;
    case 5: dst = g_wihd; break;
    case 6: dst = g_whhd; break;
    case 7: dst = g_bihd; break;
    case 8: dst = g_bhhd; break;
    case 9: dst = g_wout; break;
    default: dst = g_bout; break;
  }
  dst[idx] = v;
}

#define MFMA __builtin_amdgcn_mfma_f32_16x16x32_bf16

__global__ __launch_bounds__(256, 1) void lstm_persist(unsigned* __restrict__ bar,
                                                       void* __restrict__ outv) {
  __shared__ u16 sW0[64 * LDK];     // W hi slice (enc w_hh | dec W_eff)
  __shared__ u16 sW1[64 * LDK];     // W lo slice
  __shared__ u16 sH[16 * LDK];      // staged h (hi, then lo); fp32 scratch at phase switch
  __shared__ float sXg[4][16][16];  // gate exchange i/f/g/o
  __shared__ float sHn[16][16];     // h_new f32 for y-partials
  __shared__ float sWo[64][16];     // w_out[:, 16j:16j+16] fp32

  const int tid = threadIdx.x, bid = blockIdx.x;
  const int i = bid & 7, j = bid >> 3;
  const int wv = tid >> 6, lane = tid & 63;
  const int ln15 = lane & 15, lq = lane >> 4;
  const int m_t = tid >> 4, n_t = tid & 15;
  const int gr0 = (wv << 9) + (j << 4) + ln15;
  const bool isbf = (g_isbf16 != 0);

  // encoder w_hh slice -> hi/lo LDS
  {
    int rr = tid >> 2, c0 = (tid & 3) * 128;
    int gr = ((rr >> 4) << 9) + (j << 4) + (rr & 15);
    for (int c = c0; c < c0 + 128; c += 4) {
      f32x4 w = *(const f32x4*)&g_whhe[(size_t)gr * HH + c];
#pragma unroll
      for (int q = 0; q < 4; ++q) {
        u16 hi = f2bf(w[q]);
        sW0[rr * LDK + c + q] = hi;
        sW1[rr * LDK + c + q] = f2bf(w[q] - bf2f(hi));
      }
    }
  }
  // encoder w_ih fragments: loop-invariant, in registers (B-frag: n=ln15, k=lq*8+jj)
  s16x8 bxh0, bxh1, bxl0, bxl1;
  {
    const float* p0 = &g_wihe[(size_t)gr0 * FF + lq * 8];
#pragma unroll
    for (int jj = 0; jj < 8; ++jj) {
      float w0 = p0[jj], w1 = p0[32 + jj];
      u16 h0 = f2bf(w0), h1 = f2bf(w1);
      bxh0[jj] = (short)h0; bxl0[jj] = (short)f2bf(w0 - bf2f(h0));
      bxh1[jj] = (short)h1; bxl1[jj] = (short)f2bf(w1 - bf2f(h1));
    }
  }
  for (int idx = tid; idx < 64 * 16; idx += 256) {
    int f = idx >> 4, n = idx & 15;
    sWo[f][n] = g_wout[f * HH + (j << 4) + n];
  }
  float bias = g_bihe[gr0] + g_bhhe[gr0];

  // zero h parity 0 (hi & lo)
  g_hbuf[(size_t)(0 * BB + i * BT + m_t) * HH + (j << 4) + n_t] = 0;
  g_hbuf[(size_t)(1 * BB + i * BT + m_t) * HH + (j << 4) + n_t] = 0;

  gbar(bar, NBLK);

  float c_st = 0.f;
  const int wrow = (wv * 16 + ln15) * LDK;
  const int arow = ln15 * LDK;

  for (int g = 0; g < 2048; ++g) {
    const int cur = g & 1, nxt = cur ^ 1;
    const bool dec = (g >= 1024);

    // encoder input fragments from canonical fp32, split hi/lo
    s16x8 xh0 = {}, xl0 = {}, xh1 = {}, xl1 = {};
    if (!dec) {
      const float* xp = &g_ts[((size_t)(i * BT + ln15) * TT + g) * FF + lq * 8];
#pragma unroll
      for (int jj = 0; jj < 8; ++jj) {
        float x0 = xp[jj], x1 = xp[32 + jj];
        u16 h0 = f2bf(x0), h1 = f2bf(x1);
        xh0[jj] = (short)h0; xl0[jj] = (short)f2bf(x0 - bf2f(h0));
        xh1[jj] = (short)h1; xl1[jj] = (short)f2bf(x1 - bf2f(h1));
      }
    }

    // stage h_hi -> LDS
    {
      const u16* src = g_hbuf + (size_t)((cur * 2 + 0) * BB + i * BT) * HH;
      int cb = lane * 8;
#pragma unroll
      for (int it = 0; it < 4; ++it) {
        int r = wv + it * 4;
        *(s16x8*)&sH[r * LDK + cb] = *(const s16x8*)&src[r * HH + cb];
      }
    }
    __syncthreads();

    f32x4 acc0 = {bias, bias, bias, bias};
    f32x4 acc1 = {0.f, 0.f, 0.f, 0.f};

#pragma unroll
    for (int kt = 0; kt < 16; ++kt) {
      s16x8 a  = *(s16x8*)&sH[arow + kt * 32 + lq * 8];
      s16x8 b0 = *(s16x8*)&sW0[wrow + kt * 32 + lq * 8];
      s16x8 b1 = *(s16x8*)&sW1[wrow + kt * 32 + lq * 8];
      acc0 = MFMA(a, b0, acc0, 0, 0, 0);   // Whi . h_hi
      acc1 = MFMA(a, b1, acc1, 0, 0, 0);   // Wlo . h_hi
    }
    if (!dec) {
      acc0 = MFMA(xh0, bxh0, acc0, 0, 0, 0);
      acc0 = MFMA(xh1, bxh1, acc0, 0, 0, 0);
      acc1 = MFMA(xl0, bxh0, acc1, 0, 0, 0);
      acc1 = MFMA(xl1, bxh1, acc1, 0, 0, 0);
      acc1 = MFMA(xh0, bxl0, acc1, 0, 0, 0);
      acc1 = MFMA(xh1, bxl1, acc1, 0, 0, 0);
    }
    __syncthreads();

    // stage h_lo -> LDS, pass2: Whi . h_lo
    {
      const u16* src = g_hbuf + (size_t)((cur * 2 + 1) * BB + i * BT) * HH;
      int cb = lane * 8;
#pragma unroll
      for (int it = 0; it < 4; ++it) {
        int r = wv + it * 4;
        *(s16x8*)&sH[r * LDK + cb] = *(const s16x8*)&src[r * HH + cb];
      }
    }
    __syncthreads();
#pragma unroll
    for (int kt = 0; kt < 16; ++kt) {
      s16x8 a  = *(s16x8*)&sH[arow + kt * 32 + lq * 8];
      s16x8 b0 = *(s16x8*)&sW0[wrow + kt * 32 + lq * 8];
      acc1 = MFMA(a, b0, acc1, 0, 0, 0);
    }

    // gate exchange (D: row = lq*4+reg (batch), col = ln15 (gate unit))
    sXg[wv][lq * 4 + 0][ln15] = acc0.x + acc1.x;
    sXg[wv][lq * 4 + 1][ln15] = acc0.y + acc1.y;
    sXg[wv][lq * 4 + 2][ln15] = acc0.z + acc1.z;
    sXg[wv][lq * 4 + 3][ln15] = acc0.w + acc1.w;
    __syncthreads();

    float gi = sXg[0][m_t][n_t], gf = sXg[1][m_t][n_t];
    float gg = sXg[2][m_t][n_t], go = sXg[3][m_t][n_t];
    float si = 1.f / (1.f + __expf(-gi));
    float sf = 1.f / (1.f + __expf(-gf));
    float tg = tanhf(gg);
    float so = 1.f / (1.f + __expf(-go));
    c_st = sf * c_st + si * tg;
    float hn = so * tanhf(c_st);
    u16 hhi = f2bf(hn);
    u16 hlo = f2bf(hn - bf2f(hhi));
    g_hbuf[(size_t)((nxt * 2 + 0) * BB + i * BT + m_t) * HH + (j << 4) + n_t] = hhi;
    g_hbuf[(size_t)((nxt * 2 + 1) * BB + i * BT + m_t) * HH + (j << 4) + n_t] = hlo;

    // y-partials from this step's h (consumed by next step's emission)
    if (g >= 1023 && g < 2047) {
      sHn[m_t][n_t] = hn;
      __syncthreads();
      int fg = tid & 15, mm = tid >> 4;
      float p0 = 0, p1 = 0, p2 = 0, p3 = 0;
      for (int n = 0; n < 16; ++n) {
        float hv = sHn[mm][n];
        p0 += hv * sWo[fg * 4 + 0][n];
        p1 += hv * sWo[fg * 4 + 1][n];
        p2 += hv * sWo[fg * 4 + 2][n];
        p3 += hv * sWo[fg * 4 + 3][n];
      }
      float* pp = &g_part[(size_t)(((cur * NI + i) * NJ + j) * BT + mm) * FF + fg * 4];
      pp[0] = p0; pp[1] = p1; pp[2] = p2; pp[3] = p3;
    }

    // emit y_k from partials of step g-1 (dtype-flag-selected store)
    if (dec && j < 16 && tid < 64) {
      int k = g - 1024;
      int mm = tid >> 2, ff = (j << 2) + (tid & 3);
      float acc = g_bout[ff];
      for (int jj = 0; jj < NJ; ++jj)
        acc += g_part[(size_t)(((nxt * NI + i) * NJ + jj) * BT + mm) * FF + ff];
      size_t oidx = ((size_t)(i * BT + mm) * TT + (1023 - k)) * FF + ff;
      if (isbf) ((u16*)outv)[oidx] = f2bf(acc);
      else      ((float*)outv)[oidx] = acc;
    }

    gbar(bar, (unsigned)(g + 2) * NBLK);

    // phase switch: build fused decoder weights W_eff = Whh + Wih@Wout (hi/lo)
    if (g == 1023) {
      float* sF = (float*)sH;  // 64x64 fp32 wih_dec slice (16 KB fits in sH)
      int rr = tid >> 2;
      int grr = ((rr >> 4) << 9) + (j << 4) + (rr & 15);
      int cc = (tid & 3) * 16;
      for (int f = cc; f < cc + 16; ++f)
        sF[rr * 64 + f] = g_wihd[(size_t)grr * FF + f];
      __syncthreads();
      int c0 = (tid & 3) * 128;
      for (int c = c0; c < c0 + 128; ++c) {
        float acc = g_whhd[(size_t)grr * HH + c];
        for (int f = 0; f < FF; ++f)
          acc += sF[rr * 64 + f] * g_wout[f * HH + c];
        u16 hi = f2bf(acc);
        sW0[rr * LDK + c] = hi;
        sW1[rr * LDK + c] = f2bf(acc - bf2f(hi));
      }
      float b = g_bihd[gr0] + g_bhhd[gr0];
      int r0 = wv * 16 + ln15;
      for (int f = 0; f < FF; ++f) b += sF[r0 * 64 + f] * g_bout[f];
      bias = b;
      c_st = 0.f;
      __syncthreads();
    }
  }
}

extern "C" void kernel_launch(void* const* d_in, const int* in_sizes, int n_in,
                              void* d_out, int out_size, void* d_ws, size_t ws_size,
                              hipStream_t stream) {
  unsigned* bar = (unsigned*)d_ws;   // only 64 B of workspace used
  (void)hipMemsetAsync(bar, 0, 64, stream);

  sniff_kernel<<<1, 64, 0, stream>>>(d_in[9]);  // w_out

  const int sizes[11] = { BB * TT * FF, G4 * FF, G4 * HH, G4, G4,
                          G4 * FF, G4 * HH, G4, G4, FF * HH, FF };
  for (int k = 0; k < 11; ++k)
    convert_kernel<<<(sizes[k] + 255) / 256, 256, 0, stream>>>(d_in[k], k, sizes[k]);

  lstm_persist<<<NBLK, 256, 0, stream>>>(bar, d_out);
}

// Round 5
// 21008.061 us; speedup vs baseline: 1.7298x; 1.7298x over previous
//
#include <hip/hip_runtime.h>
#include <math.h>

#define BB 128
#define TT 1024
#define FF 64
#define HH 512
#define G4 2048            // 4*HH gate rows
#define NI 8               // batch groups (independent!)
#define NJ 32              // hidden slices per group
#define BT 16
#define NBLK 256
#define NG 32              // blocks per sync group
#define LDK 520            // padded row: 1040B stride -> balanced banks for b128

typedef float f32x4 __attribute__((ext_vector_type(4)));
typedef short s16x8 __attribute__((ext_vector_type(8)));
typedef unsigned short u16;

// ---- canonical fp32 inputs ----
__device__ float g_ts[BB * TT * FF];
__device__ float g_wihe[G4 * FF];
__device__ float g_whhe[G4 * HH];
__device__ float g_bihe[G4], g_bhhe[G4], g_bihd[G4], g_bhhd[G4];
__device__ float g_wihd[G4 * FF];
__device__ float g_whhd[G4 * HH];
__device__ float g_wout[FF * HH];
__device__ float g_bout[FF];
// ---- precomputed fused decoder weights ----
__device__ float g_weff[G4 * HH];
__device__ float g_beff[G4];
// ---- inter-block state ----
__device__ u16   g_hbuf[2 * 2 * BB * HH];        // [parity][hi/lo][BB][HH]
__device__ float g_part[4 * NI * NJ * BT * FF];  // depth-4 ring
__device__ int   g_isbf16;

__device__ __forceinline__ float bf2f(u16 u) {
  union { unsigned u; float f; } x; x.u = ((unsigned)u) << 16; return x.f;
}
__device__ __forceinline__ u16 f2bf(float f) {
  union { float f; unsigned u; } x; x.f = f;
  unsigned r = x.u + 0x7fffu + ((x.u >> 16) & 1u);
  return (u16)(r >> 16);
}

__global__ void sniff_kernel(const void* wout) {
  __shared__ int cnt[64];
  int t = threadIdx.x;
  const unsigned* d = (const unsigned*)wout;
  int c = 0;
  for (int k = t; k < 1024; k += 64) {
    unsigned b = (d[k] >> 8) & 0x7fu;
    c += (b >= 0x30u && b <= 0x3eu) ? 1 : 0;
  }
  cnt[t] = c;
  __syncthreads();
  if (t == 0) {
    int s = 0;
    for (int k = 0; k < 64; ++k) s += cnt[k];
    g_isbf16 = (s > 512) ? 1 : 0;
  }
}

__global__ void convert_kernel(const void* __restrict__ src, int which, int n) {
  int idx = blockIdx.x * 256 + threadIdx.x;
  if (idx >= n) return;
  float v;
  if (g_isbf16) v = bf2f(((const u16*)src)[idx]);
  else          v = ((const float*)src)[idx];
  float* dst;
  switch (which) {
    case 0: dst = g_ts;   break;
    case 1: dst = g_wihe; break;
    case 2: dst = g_whhe; break;
    case 3: dst = g_bihe; break;
    case 4: dst = g_bhhe; break;
    case 5: dst = g_wihd; break;
    case 6: dst = g_whhd; break;
    case 7: dst = g_bihd; break;
    case 8: dst = g_bhhd; break;
    case 9: dst = g_wout; break;
    default: dst = g_bout; break;
  }
  dst[idx] = v;
}

// W_eff = w_hh_dec + w_ih_dec @ w_out ; b_eff = b_ihd + b_hhd + w_ih_dec @ b_out
__global__ void prep_kernel() {
  int idx = blockIdx.x * 256 + threadIdx.x;   // 0 .. G4*HH
  int r = idx >> 9, c = idx & 511;
  float acc = g_whhd[idx];
  const float* wr = &g_wihd[r * FF];
  for (int f = 0; f < FF; ++f) acc += wr[f] * g_wout[f * HH + c];
  g_weff[idx] = acc;
  if (idx < G4) {
    float b = g_bihd[idx] + g_bhhd[idx];
    for (int f = 0; f < FF; ++f) b += g_wihd[idx * FF + f] * g_bout[f];
    g_beff[idx] = b;
  }
}

#define MFMA __builtin_amdgcn_mfma_f32_16x16x32_bf16

__global__ __launch_bounds__(256, 1) void lstm_persist(unsigned* __restrict__ bar,
                                                       void* __restrict__ outv) {
  __shared__ u16 sH[32 * LDK];      // rows 0-15: h_hi, 16-31: h_lo
  __shared__ float sXg[4][16][16];  // gate exchange i/f/g/o
  __shared__ float sHn[16][16];     // h_new f32 for y-partials
  __shared__ float sWo[64][16];     // w_out[:, 16j:16j+16]

  const int tid = threadIdx.x, bid = blockIdx.x;
  const int i = bid & 7, j = bid >> 3;      // group i ~ XCD-affine
  const int wv = tid >> 6, lane = tid & 63;
  const int ln15 = lane & 15, lq = lane >> 4;
  const int m_t = tid >> 4, n_t = tid & 15;
  const int gr0 = (wv << 9) + (j << 4) + ln15;
  const bool isbf = (g_isbf16 != 0);
  unsigned* mybar = bar + i * 64;           // per-group counter, 256B apart

  // ---- hidden weights -> REGISTERS (hi/lo bf16), encoder phase ----
  s16x8 wh[16], wl[16];
#pragma unroll
  for (int kt = 0; kt < 16; ++kt) {
    const float* p = &g_whhe[(size_t)gr0 * HH + kt * 32 + lq * 8];
#pragma unroll
    for (int q = 0; q < 8; ++q) {
      float w = p[q]; u16 hi = f2bf(w);
      wh[kt][q] = (short)hi; wl[kt][q] = (short)f2bf(w - bf2f(hi));
    }
  }
  s16x8 bxh0, bxh1, bxl0, bxl1;   // encoder x-weight fragments
  {
    const float* p0 = &g_wihe[(size_t)gr0 * FF + lq * 8];
#pragma unroll
    for (int q = 0; q < 8; ++q) {
      float w0 = p0[q], w1 = p0[32 + q];
      u16 h0 = f2bf(w0), h1 = f2bf(w1);
      bxh0[q] = (short)h0; bxl0[q] = (short)f2bf(w0 - bf2f(h0));
      bxh1[q] = (short)h1; bxl1[q] = (short)f2bf(w1 - bf2f(h1));
    }
  }
  for (int idx = tid; idx < 64 * 16; idx += 256) {
    int f = idx >> 4, n = idx & 15;
    sWo[f][n] = g_wout[f * HH + (j << 4) + n];
  }
  float bias = g_bihe[gr0] + g_bhhe[gr0];

  // zero h parity 0 (hi & lo)
  g_hbuf[(size_t)(0 * BB + i * BT + m_t) * HH + (j << 4) + n_t] = 0;
  g_hbuf[(size_t)(1 * BB + i * BT + m_t) * HH + (j << 4) + n_t] = 0;

  // initial group barrier (publish zero-init)
  __syncthreads();
  if (tid == 0) {
    __hip_atomic_fetch_add(mybar, 1u, __ATOMIC_RELEASE, __HIP_MEMORY_SCOPE_AGENT);
    while (__hip_atomic_load(mybar, __ATOMIC_RELAXED, __HIP_MEMORY_SCOPE_AGENT) < NG)
      __builtin_amdgcn_s_sleep(1);
    (void)__hip_atomic_load(mybar, __ATOMIC_ACQUIRE, __HIP_MEMORY_SCOPE_AGENT);
  }
  __syncthreads();

  float c_st = 0.f;
  const int arow = ln15 * LDK;
  const int koff = lq * 8;

  for (int g = 0; g < 2049; ++g) {
    const int cur = g & 1, nxt = cur ^ 1;
    const bool run = (g < 2048);
    float hn = 0.f;

    if (run) {
      const bool enc = (g < 1024);
      s16x8 xh0 = {}, xl0 = {}, xh1 = {}, xl1 = {};
      if (enc) {
        const float* xp = &g_ts[((size_t)(i * BT + ln15) * TT + g) * FF + lq * 8];
#pragma unroll
        for (int q = 0; q < 8; ++q) {
          float x0 = xp[q], x1 = xp[32 + q];
          u16 h0 = f2bf(x0), h1 = f2bf(x1);
          xh0[q] = (short)h0; xl0[q] = (short)f2bf(x0 - bf2f(h0));
          xh1[q] = (short)h1; xl1[q] = (short)f2bf(x1 - bf2f(h1));
        }
      }
      // stage h hi+lo in ONE round
      {
        const u16* srcH = g_hbuf + ((size_t)(cur * 2 + 0) * BB + i * BT) * HH;
        const u16* srcL = g_hbuf + ((size_t)(cur * 2 + 1) * BB + i * BT) * HH;
        int cb = lane * 8;
#pragma unroll
        for (int it = 0; it < 4; ++it) {
          int r = wv + it * 4;
          *(s16x8*)&sH[r * LDK + cb]        = *(const s16x8*)&srcH[(size_t)r * HH + cb];
          *(s16x8*)&sH[(16 + r) * LDK + cb] = *(const s16x8*)&srcL[(size_t)r * HH + cb];
        }
      }
      __syncthreads();

      f32x4 acc0 = {bias, bias, bias, bias};
      f32x4 acc1 = {0.f, 0.f, 0.f, 0.f};
      f32x4 acc2 = {0.f, 0.f, 0.f, 0.f};
#pragma unroll
      for (int kt = 0; kt < 16; ++kt) {
        s16x8 ah = *(s16x8*)&sH[arow + kt * 32 + koff];
        s16x8 al = *(s16x8*)&sH[16 * LDK + arow + kt * 32 + koff];
        acc0 = MFMA(ah, wh[kt], acc0, 0, 0, 0);   // Whi . h_hi
        acc1 = MFMA(al, wh[kt], acc1, 0, 0, 0);   // Whi . h_lo
        acc2 = MFMA(ah, wl[kt], acc2, 0, 0, 0);   // Wlo . h_hi
      }
      if (enc) {
        acc0 = MFMA(xh0, bxh0, acc0, 0, 0, 0);
        acc0 = MFMA(xh1, bxh1, acc0, 0, 0, 0);
        acc1 = MFMA(xl0, bxh0, acc1, 0, 0, 0);
        acc1 = MFMA(xl1, bxh1, acc1, 0, 0, 0);
        acc2 = MFMA(xh0, bxl0, acc2, 0, 0, 0);
        acc2 = MFMA(xh1, bxl1, acc2, 0, 0, 0);
      }
      sXg[wv][lq * 4 + 0][ln15] = acc0.x + acc1.x + acc2.x;
      sXg[wv][lq * 4 + 1][ln15] = acc0.y + acc1.y + acc2.y;
      sXg[wv][lq * 4 + 2][ln15] = acc0.z + acc1.z + acc2.z;
      sXg[wv][lq * 4 + 3][ln15] = acc0.w + acc1.w + acc2.w;
      __syncthreads();

      float gi = sXg[0][m_t][n_t], gf = sXg[1][m_t][n_t];
      float gg = sXg[2][m_t][n_t], go = sXg[3][m_t][n_t];
      float si = 1.f / (1.f + __expf(-gi));
      float sf = 1.f / (1.f + __expf(-gf));
      float tg = tanhf(gg);
      float so = 1.f / (1.f + __expf(-go));
      c_st = sf * c_st + si * tg;
      hn = so * tanhf(c_st);
      u16 hhi = f2bf(hn);
      u16 hlo = f2bf(hn - bf2f(hhi));
      g_hbuf[(size_t)((nxt * 2 + 0) * BB + i * BT + m_t) * HH + (j << 4) + n_t] = hhi;
      g_hbuf[(size_t)((nxt * 2 + 1) * BB + i * BT + m_t) * HH + (j << 4) + n_t] = hlo;
    }

    // ---- publish h, ARRIVE (release) ----
    __syncthreads();
    if (run && tid == 0)
      __hip_atomic_fetch_add(mybar, 1u, __ATOMIC_RELEASE, __HIP_MEMORY_SCOPE_AGENT);

    // ---- off-critical-path work in the arrive->wait window ----
    if (g >= 1023 && g < 2047) {   // y-partials of h_start(g-1023), slot g&3
      sHn[m_t][n_t] = hn;
      __syncthreads();
      int fg = tid & 15, mm = tid >> 4;
      float p0 = 0, p1 = 0, p2 = 0, p3 = 0;
      for (int n = 0; n < 16; ++n) {
        float hv = sHn[mm][n];
        p0 += hv * sWo[fg * 4 + 0][n];
        p1 += hv * sWo[fg * 4 + 1][n];
        p2 += hv * sWo[fg * 4 + 2][n];
        p3 += hv * sWo[fg * 4 + 3][n];
      }
      float* pp = &g_part[(size_t)((((g & 3) * NI + i) * NJ + j) * BT + mm) * FF + fg * 4];
      pp[0] = p0; pp[1] = p1; pp[2] = p2; pp[3] = p3;
    }
    if (g >= 1025 && j < 16 && tid < 64) {   // emit k = g-1025 from slot (g-2)&3
      int k = g - 1025;
      int mm = tid >> 2, ff = (j << 2) + (tid & 3);
      int slot = (g - 2) & 3;
      float acc = g_bout[ff];
      for (int jj = 0; jj < NJ; ++jj)
        acc += g_part[(size_t)(((slot * NI + i) * NJ + jj) * BT + mm) * FF + ff];
      size_t oidx = ((size_t)(i * BT + mm) * TT + (1023 - k)) * FF + ff;
      if (isbf) ((u16*)outv)[oidx] = f2bf(acc);
      else      ((float*)outv)[oidx] = acc;
    }

    // ---- WAIT (acquire) ----
    if (run) {
      if (tid == 0) {
        unsigned target = (unsigned)(g + 2) * NG;
        while (__hip_atomic_load(mybar, __ATOMIC_RELAXED, __HIP_MEMORY_SCOPE_AGENT) < target)
          __builtin_amdgcn_s_sleep(1);
        (void)__hip_atomic_load(mybar, __ATOMIC_ACQUIRE, __HIP_MEMORY_SCOPE_AGENT);
      }
      __syncthreads();
    }

    // phase switch: reload registers with fused decoder weights
    if (g == 1023) {
#pragma unroll
      for (int kt = 0; kt < 16; ++kt) {
        const float* p = &g_weff[(size_t)gr0 * HH + kt * 32 + lq * 8];
#pragma unroll
        for (int q = 0; q < 8; ++q) {
          float w = p[q]; u16 hi = f2bf(w);
          wh[kt][q] = (short)hi; wl[kt][q] = (short)f2bf(w - bf2f(hi));
        }
      }
      bias = g_beff[gr0];
      c_st = 0.f;
    }
  }
}

extern "C" void kernel_launch(void* const* d_in, const int* in_sizes, int n_in,
                              void* d_out, int out_size, void* d_ws, size_t ws_size,
                              hipStream_t stream) {
  unsigned* bar = (unsigned*)d_ws;   // 8 group counters, 256B apart
  (void)hipMemsetAsync(bar, 0, 2048, stream);

  sniff_kernel<<<1, 64, 0, stream>>>(d_in[9]);  // w_out

  const int sizes[11] = { BB * TT * FF, G4 * FF, G4 * HH, G4, G4,
                          G4 * FF, G4 * HH, G4, G4, FF * HH, FF };
  for (int k = 0; k < 11; ++k)
    convert_kernel<<<(sizes[k] + 255) / 256, 256, 0, stream>>>(d_in[k], k, sizes[k]);

  prep_kernel<<<(G4 * HH) / 256, 256, 0, stream>>>();

  lstm_persist<<<NBLK, 256, 0, stream>>>(bar, d_out);
}

// Round 6
// 15722.311 us; speedup vs baseline: 2.3113x; 1.3362x over previous
//
#include <hip/hip_runtime.h>
#include <math.h>

#define BB 128
#define TT 1024
#define FF 64
#define HH 512
#define G4 2048            // 4*HH gate rows
#define NI 8               // batch groups (independent)
#define NJ 32              // hidden slices per group
#define BT 16
#define NBLK 256
#define LDK 520            // padded LDS row (u16): 1040B stride

typedef float f32x4 __attribute__((ext_vector_type(4)));
typedef short s16x8 __attribute__((ext_vector_type(8)));
typedef unsigned short u16;
typedef unsigned long long u64;

// ---- canonical fp32 inputs ----
__device__ float g_ts[BB * TT * FF];
__device__ float g_wihe[G4 * FF];
__device__ float g_whhe[G4 * HH];
__device__ float g_bihe[G4], g_bhhe[G4], g_bihd[G4], g_bhhd[G4];
__device__ float g_wihd[G4 * FF];
__device__ float g_whhd[G4 * HH];
__device__ float g_wout[FF * HH];
__device__ float g_bout[FF];
// ---- precomputed fused decoder weights ----
__device__ float g_weff[G4 * HH];
__device__ float g_beff[G4];
// ---- inter-block state (always accessed with agent-scope atomics) ----
__device__ __align__(16) u16 g_hbuf[2 * 2 * BB * HH];   // [parity][hi/lo][BB][HH]
__device__ float g_part[4 * NI * NJ * BT * FF];         // depth-4 ring
__device__ int   g_isbf16;

__device__ __forceinline__ float bf2f(u16 u) {
  union { unsigned u; float f; } x; x.u = ((unsigned)u) << 16; return x.f;
}
__device__ __forceinline__ u16 f2bf(float f) {
  union { float f; unsigned u; } x; x.f = f;
  unsigned r = x.u + 0x7fffu + ((x.u >> 16) & 1u);
  return (u16)(r >> 16);
}

__global__ void sniff_kernel(const void* wout) {
  __shared__ int cnt[64];
  int t = threadIdx.x;
  const unsigned* d = (const unsigned*)wout;
  int c = 0;
  for (int k = t; k < 1024; k += 64) {
    unsigned b = (d[k] >> 8) & 0x7fu;
    c += (b >= 0x30u && b <= 0x3eu) ? 1 : 0;
  }
  cnt[t] = c;
  __syncthreads();
  if (t == 0) {
    int s = 0;
    for (int k = 0; k < 64; ++k) s += cnt[k];
    g_isbf16 = (s > 512) ? 1 : 0;
  }
}

__global__ void convert_kernel(const void* __restrict__ src, int which, int n) {
  int idx = blockIdx.x * 256 + threadIdx.x;
  if (idx >= n) return;
  float v;
  if (g_isbf16) v = bf2f(((const u16*)src)[idx]);
  else          v = ((const float*)src)[idx];
  float* dst;
  switch (which) {
    case 0: dst = g_ts;   break;
    case 1: dst = g_wihe; break;
    case 2: dst = g_whhe; break;
    case 3: dst = g_bihe; break;
    case 4: dst = g_bhhe; break;
    case 5: dst = g_wihd; break;
    case 6: dst = g_whhd; break;
    case 7: dst = g_bihd; break;
    case 8: dst = g_bhhd; break;
    case 9: dst = g_wout; break;
    default: dst = g_bout; break;
  }
  dst[idx] = v;
}

// W_eff = w_hh_dec + w_ih_dec @ w_out ; b_eff = b_ihd + b_hhd + w_ih_dec @ b_out
__global__ void prep_kernel() {
  int idx = blockIdx.x * 256 + threadIdx.x;
  int r = idx >> 9, c = idx & 511;
  float acc = g_whhd[idx];
  const float* wr = &g_wihd[r * FF];
  for (int f = 0; f < FF; ++f) acc += wr[f] * g_wout[f * HH + c];
  g_weff[idx] = acc;
  if (idx < G4) {
    float b = g_bihd[idx] + g_bhhd[idx];
    for (int f = 0; f < FF; ++f) b += g_wihd[idx * FF + f] * g_bout[f];
    g_beff[idx] = b;
  }
}

#define MFMA __builtin_amdgcn_mfma_f32_16x16x32_bf16
#define A_LD(p)  __hip_atomic_load((p), __ATOMIC_RELAXED, __HIP_MEMORY_SCOPE_AGENT)
#define A_ST(p, v) __hip_atomic_store((p), (v), __ATOMIC_RELAXED, __HIP_MEMORY_SCOPE_AGENT)

__global__ __launch_bounds__(256, 1) void lstm_persist(unsigned* __restrict__ bar,
                                                       void* __restrict__ outv) {
  __shared__ u16 sH[32 * LDK];      // rows 0-15: h_hi, 16-31: h_lo
  __shared__ float sXg[4][16][16];  // gate exchange i/f/g/o
  __shared__ float sHn[16][16];     // h_new f32 for y-partials
  __shared__ float sWo[64][16];     // w_out[:, 16j:16j+16]

  const int tid = threadIdx.x, bid = blockIdx.x;
  const int i = bid & 7, j = bid >> 3;      // group i ~ XCD-affine
  const int wv = tid >> 6, lane = tid & 63;
  const int ln15 = lane & 15, lq = lane >> 4;
  const int m_t = tid >> 4, n_t = tid & 15;
  const int gr0 = (wv << 9) + (j << 4) + ln15;
  const bool isbf = (g_isbf16 != 0);
  unsigned* flags = bar + i * 64;           // 32 flags per group, 256B apart
  unsigned* myflag = flags + j;

  // ---- hidden weights -> registers (hi/lo bf16), encoder phase ----
  s16x8 wh[16], wl[16];
#pragma unroll
  for (int kt = 0; kt < 16; ++kt) {
    const float* p = &g_whhe[(size_t)gr0 * HH + kt * 32 + lq * 8];
#pragma unroll
    for (int q = 0; q < 8; ++q) {
      float w = p[q]; u16 hi = f2bf(w);
      wh[kt][q] = (short)hi; wl[kt][q] = (short)f2bf(w - bf2f(hi));
    }
  }
  s16x8 bxh0, bxh1, bxl0, bxl1;   // encoder x-weight fragments
  {
    const float* p0 = &g_wihe[(size_t)gr0 * FF + lq * 8];
#pragma unroll
    for (int q = 0; q < 8; ++q) {
      float w0 = p0[q], w1 = p0[32 + q];
      u16 h0 = f2bf(w0), h1 = f2bf(w1);
      bxh0[q] = (short)h0; bxl0[q] = (short)f2bf(w0 - bf2f(h0));
      bxh1[q] = (short)h1; bxl1[q] = (short)f2bf(w1 - bf2f(h1));
    }
  }
  for (int idx = tid; idx < 64 * 16; idx += 256) {
    int f = idx >> 4, n = idx & 15;
    sWo[f][n] = g_wout[f * HH + (j << 4) + n];
  }
  float bias = g_bihe[gr0] + g_bhhe[gr0];

  // zero h parity 0 (hi & lo) via write-through stores
  A_ST(&g_hbuf[(size_t)(0 * BB + i * BT + m_t) * HH + (j << 4) + n_t], (u16)0);
  A_ST(&g_hbuf[(size_t)(1 * BB + i * BT + m_t) * HH + (j << 4) + n_t], (u16)0);

  // publish init: drain, flag epoch 1, wait group
  asm volatile("s_waitcnt vmcnt(0)" ::: "memory");
  __syncthreads();
  if (tid == 0)
    __hip_atomic_store(myflag, 1u, __ATOMIC_RELEASE, __HIP_MEMORY_SCOPE_AGENT);
  if (tid < 64) {
    unsigned* fp = flags + (lane & 31);
    while (true) {
      unsigned v = A_LD(fp);
      if (__ballot(v >= 1u) == ~0ull) break;
      __builtin_amdgcn_s_sleep(2);
    }
  }
  asm volatile("" ::: "memory");
  __syncthreads();

  float c_st = 0.f;
  const int arow = ln15 * LDK;
  const int koff = lq * 8;

  for (int g = 0; g <= 2048; ++g) {
    const int cur = g & 1, nxt = cur ^ 1;
    const bool run = (g < 2048);
    float hn = 0.f;

    if (run) {
      const bool enc = (g < 1024);
      s16x8 xh0 = {}, xl0 = {}, xh1 = {}, xl1 = {};
      if (enc) {
        const float* xp = &g_ts[((size_t)(i * BT + ln15) * TT + g) * FF + lq * 8];
#pragma unroll
        for (int q = 0; q < 8; ++q) {
          float x0 = xp[q], x1 = xp[32 + q];
          u16 h0 = f2bf(x0), h1 = f2bf(x1);
          xh0[q] = (short)h0; xl0[q] = (short)f2bf(x0 - bf2f(h0));
          xh1[q] = (short)h1; xl1[q] = (short)f2bf(x1 - bf2f(h1));
        }
      }
      // stage h hi+lo: bypass u64 loads -> LDS b128 writes
      {
        int r = tid >> 4, cb = (tid & 15) * 32;
        const u64* ph = (const u64*)(g_hbuf + ((size_t)(cur * 2 + 0) * BB + i * BT + r) * HH + cb);
        const u64* pl = (const u64*)(g_hbuf + ((size_t)(cur * 2 + 1) * BB + i * BT + r) * HH + cb);
        u64 hq[8], lqv[8];
#pragma unroll
        for (int k = 0; k < 8; ++k) hq[k] = A_LD(ph + k);
#pragma unroll
        for (int k = 0; k < 8; ++k) lqv[k] = A_LD(pl + k);
        union Qu { u64 q[2]; s16x8 v; };
#pragma unroll
        for (int k = 0; k < 4; ++k) {
          Qu a; a.q[0] = hq[2 * k]; a.q[1] = hq[2 * k + 1];
          *(s16x8*)&sH[r * LDK + cb + 8 * k] = a.v;
          Qu b; b.q[0] = lqv[2 * k]; b.q[1] = lqv[2 * k + 1];
          *(s16x8*)&sH[(16 + r) * LDK + cb + 8 * k] = b.v;
        }
      }
      __syncthreads();

      f32x4 acc0 = {bias, bias, bias, bias};
      f32x4 acc1 = {0.f, 0.f, 0.f, 0.f};
      f32x4 acc2 = {0.f, 0.f, 0.f, 0.f};
#pragma unroll
      for (int kt = 0; kt < 16; ++kt) {
        s16x8 ah = *(s16x8*)&sH[arow + kt * 32 + koff];
        s16x8 al = *(s16x8*)&sH[16 * LDK + arow + kt * 32 + koff];
        acc0 = MFMA(ah, wh[kt], acc0, 0, 0, 0);   // Whi . h_hi
        acc1 = MFMA(al, wh[kt], acc1, 0, 0, 0);   // Whi . h_lo
        acc2 = MFMA(ah, wl[kt], acc2, 0, 0, 0);   // Wlo . h_hi
      }
      if (enc) {
        acc0 = MFMA(xh0, bxh0, acc0, 0, 0, 0);
        acc0 = MFMA(xh1, bxh1, acc0, 0, 0, 0);
        acc1 = MFMA(xl0, bxh0, acc1, 0, 0, 0);
        acc1 = MFMA(xl1, bxh1, acc1, 0, 0, 0);
        acc2 = MFMA(xh0, bxl0, acc2, 0, 0, 0);
        acc2 = MFMA(xh1, bxl1, acc2, 0, 0, 0);
      }
      sXg[wv][lq * 4 + 0][ln15] = acc0.x + acc1.x + acc2.x;
      sXg[wv][lq * 4 + 1][ln15] = acc0.y + acc1.y + acc2.y;
      sXg[wv][lq * 4 + 2][ln15] = acc0.z + acc1.z + acc2.z;
      sXg[wv][lq * 4 + 3][ln15] = acc0.w + acc1.w + acc2.w;
      __syncthreads();

      float gi = sXg[0][m_t][n_t], gf = sXg[1][m_t][n_t];
      float gg = sXg[2][m_t][n_t], go = sXg[3][m_t][n_t];
      float si = 1.f / (1.f + __expf(-gi));
      float sf = 1.f / (1.f + __expf(-gf));
      float tg = tanhf(gg);
      float so = 1.f / (1.f + __expf(-go));
      c_st = sf * c_st + si * tg;
      hn = so * tanhf(c_st);
      u16 hhi = f2bf(hn);
      u16 hlo = f2bf(hn - bf2f(hhi));
      A_ST(&g_hbuf[(size_t)((nxt * 2 + 0) * BB + i * BT + m_t) * HH + (j << 4) + n_t], hhi);
      A_ST(&g_hbuf[(size_t)((nxt * 2 + 1) * BB + i * BT + m_t) * HH + (j << 4) + n_t], hlo);

      // ---- ARRIVE: drain write-through stores, then flag ----
      asm volatile("s_waitcnt vmcnt(0)" ::: "memory");
      __syncthreads();
      if (tid == 0)
        __hip_atomic_store(myflag, (unsigned)(g + 2), __ATOMIC_RELEASE,
                           __HIP_MEMORY_SCOPE_AGENT);
    }

    // ---- off-critical-path work in the arrive->wait window ----
    if (g >= 1023 && g < 2047) {   // y-partials of this step's h, slot g&3
      sHn[m_t][n_t] = hn;
      __syncthreads();
      int fg = tid & 15, mm = tid >> 4;
      float p0 = 0, p1 = 0, p2 = 0, p3 = 0;
      for (int n = 0; n < 16; ++n) {
        float hv = sHn[mm][n];
        p0 += hv * sWo[fg * 4 + 0][n];
        p1 += hv * sWo[fg * 4 + 1][n];
        p2 += hv * sWo[fg * 4 + 2][n];
        p3 += hv * sWo[fg * 4 + 3][n];
      }
      float* pp = &g_part[(size_t)((((g & 3) * NI + i) * NJ + j) * BT + mm) * FF + fg * 4];
      A_ST(pp + 0, p0); A_ST(pp + 1, p1); A_ST(pp + 2, p2); A_ST(pp + 3, p3);
    }
    if (g >= 1025 && j < 16 && tid < 64) {   // emit k = g-1025 from slot (g-2)&3
      int k = g - 1025;
      int mm = tid >> 2, ff = (j << 2) + (tid & 3);
      int slot = (g - 2) & 3;
      float acc = g_bout[ff];
      for (int jj = 0; jj < NJ; ++jj)
        acc += A_LD(&g_part[(size_t)(((slot * NI + i) * NJ + jj) * BT + mm) * FF + ff]);
      size_t oidx = ((size_t)(i * BT + mm) * TT + (1023 - k)) * FF + ff;
      if (isbf) ((u16*)outv)[oidx] = f2bf(acc);
      else      ((float*)outv)[oidx] = acc;
    }

    // ---- WAIT: wave 0 polls all 32 group flags in one vector round ----
    if (run) {
      if (tid < 64) {
        unsigned* fp = flags + (lane & 31);
        unsigned target = (unsigned)(g + 2);
        while (true) {
          unsigned v = A_LD(fp);
          if (__ballot(v >= target) == ~0ull) break;
          __builtin_amdgcn_s_sleep(2);
        }
      }
      asm volatile("" ::: "memory");
      __syncthreads();
    }

    // phase switch: reload registers with fused decoder weights
    if (g == 1023) {
#pragma unroll
      for (int kt = 0; kt < 16; ++kt) {
        const float* p = &g_weff[(size_t)gr0 * HH + kt * 32 + lq * 8];
#pragma unroll
        for (int q = 0; q < 8; ++q) {
          float w = p[q]; u16 hi = f2bf(w);
          wh[kt][q] = (short)hi; wl[kt][q] = (short)f2bf(w - bf2f(hi));
        }
      }
      bias = g_beff[gr0];
      c_st = 0.f;
    }
  }
}

extern "C" void kernel_launch(void* const* d_in, const int* in_sizes, int n_in,
                              void* d_out, int out_size, void* d_ws, size_t ws_size,
                              hipStream_t stream) {
  unsigned* bar = (unsigned*)d_ws;   // 8 groups x 32 flags, 256B apart
  (void)hipMemsetAsync(bar, 0, 2048, stream);

  sniff_kernel<<<1, 64, 0, stream>>>(d_in[9]);  // w_out

  const int sizes[11] = { BB * TT * FF, G4 * FF, G4 * HH, G4, G4,
                          G4 * FF, G4 * HH, G4, G4, FF * HH, FF };
  for (int k = 0; k < 11; ++k)
    convert_kernel<<<(sizes[k] + 255) / 256, 256, 0, stream>>>(d_in[k], k, sizes[k]);

  prep_kernel<<<(G4 * HH) / 256, 256, 0, stream>>>();

  lstm_persist<<<NBLK, 256, 0, stream>>>(bar, d_out);
}